// Round 5
// baseline (284.431 us; speedup 1.0000x reference)
//
#include <hip/hip_runtime.h>
#include <hip/hip_bf16.h>

#define BATCH 8192
#define NLAY  60
#define NH    64
#define ROWS  16
#define TPB   512
#define SX    136     // xh row stride (ushort), rows 16B-aligned
#define SM    968     // memAll row stride (ushort)
#define SP    273     // preactS row stride (float) — odd-ish to spread banks
#define SI    244     // inmB row stride (ushort)

typedef unsigned short ushort_t;
typedef __attribute__((ext_vector_type(8))) short short8;
typedef __attribute__((ext_vector_type(4))) short short4v;
typedef __attribute__((ext_vector_type(4))) float f32x4;
typedef __attribute__((ext_vector_type(4))) float f4v;

__device__ __forceinline__ float rcp_(float x) { return __builtin_amdgcn_rcpf(x); }
__device__ __forceinline__ float sigm_(float x) { return rcp_(1.0f + __expf(-x)); }
__device__ __forceinline__ float tanh_(float x) { return 1.0f - 2.0f * rcp_(__expf(2.0f * x) + 1.0f); }
__device__ __forceinline__ ushort_t f2bu(float f) {
  unsigned u = __float_as_uint(f);
  return (ushort_t)((u + 0x7FFFu + ((u >> 16) & 1u)) >> 16);
}
__device__ __forceinline__ float b2fu(ushort_t b) { return __uint_as_float(((unsigned)b) << 16); }
__device__ __forceinline__ f32x4 mfma16(short8 a, short8 b, f32x4 c) {
  return __builtin_amdgcn_mfma_f32_16x16x32_bf16(a, b, c, 0, 0, 0);
}

// ---- Pre-pass: pack weights into MFMA B-fragment order (bf16 bits) ----
// K-order for LSTM1: [x(0..63) | h(64..127) | mem(128..143) | pad(144..159)]
// W1f [w'][g][ks5][512] @0 ; W2f [w'][g][ks4][512] @40960 ; WlF @73728 ;
// WcF (Wo@Wl) @74752 ; WsF (Wso) @75776. Total 76800 ushorts.
__global__ void wtranspose(const float* __restrict__ Wih1, const float* __restrict__ Whh1,
                           const float* __restrict__ Wih2, const float* __restrict__ Whh2,
                           const float* __restrict__ Wl,   const float* __restrict__ Wo,
                           const float* __restrict__ Wso,  ushort_t* __restrict__ frag) {
  int e = blockIdx.x * 256 + threadIdx.x;
  float v;
  if (e < 40960) {
    int j = e & 7, lx = (e >> 3) & 63, rest = e >> 9;
    int ks = rest % 5, gw = rest / 5;
    int g = gw & 3, wv = gw >> 2;
    int row = g * 64 + wv * 16 + (lx & 15);
    int k = ks * 32 + (lx >> 4) * 8 + j;
    v = (k < 64)  ? Wih1[row * 80 + k]
      : (k < 128) ? Whh1[row * 64 + (k - 64)]
      : (k < 144) ? Wih1[row * 80 + 64 + (k - 128)]
      : 0.0f;
  } else if (e < 73728) {
    int e2 = e - 40960;
    int j = e2 & 7, lx = (e2 >> 3) & 63, rest = e2 >> 9;
    int ks = rest & 3, g = (rest >> 2) & 3, wv = rest >> 4;
    int row = g * 64 + wv * 16 + (lx & 15);
    int k = ks * 32 + (lx >> 4) * 8 + j;
    v = (k < 64) ? Wih2[row * 64 + k] : Whh2[row * 64 + (k - 64)];
  } else if (e < 74752) {
    int e3 = e - 73728;
    int j = e3 & 7, lx = (e3 >> 3) & 63, ks = e3 >> 9;
    int n = lx & 15, k = ks * 32 + (lx >> 4) * 8 + j;
    v = Wl[n * 64 + k];
  } else if (e < 75776) {
    int e4 = e - 74752;
    int j = e4 & 7, lx = (e4 >> 3) & 63, ks = e4 >> 9;
    int n = lx & 15, k = ks * 32 + (lx >> 4) * 8 + j;
    v = 0.0f;
    if (n < 4) {
#pragma unroll
      for (int m = 0; m < 16; ++m) v += Wo[n * 16 + m] * Wl[m * 64 + k];
    }
  } else {
    int e5 = e - 75776;
    int j = e5 & 7, lx = (e5 >> 3) & 63, ks = e5 >> 9;
    int n = lx & 15, k = ks * 32 + (lx >> 4) * 8 + j;
    v = (n < 3) ? Wso[n * 64 + k] : 0.0f;
  }
  frag[e] = f2bu(v);
}

// ---- Fused LSTM: 512 blocks x 512 thr (8 waves), 16 rows/block, 4 waves/SIMD ----
// Wave wv: unit-block wq=wv>>1 (units wq*16..+15), gate pair gp=wv&1 (gates 2gp,2gp+1).
// GEMM: each wave 2 gate-tiles x (5|4) ks. Preacts redistributed via LDS; epilogue
// is 2 cells/thread (rows 2wv,2wv+1; unit=lane).
__global__ __launch_bounds__(TPB, 4)
void lstm_fused(const float* __restrict__ inputs_main, const float* __restrict__ inputs_aux,
                const float* __restrict__ rnn1_mem,
                const float* __restrict__ Wi,  const float* __restrict__ bi,
                const float* __restrict__ Ws1, const float* __restrict__ bs1,
                const float* __restrict__ Ws2, const float* __restrict__ bs2,
                const float* __restrict__ Wt1, const float* __restrict__ bt1,
                const float* __restrict__ Wt2, const float* __restrict__ bt2,
                const float* __restrict__ bih1, const float* __restrict__ bhh1,
                const float* __restrict__ bih2, const float* __restrict__ bhh2,
                const float* __restrict__ bl,  const float* __restrict__ Wo,
                const float* __restrict__ bo,  const float* __restrict__ bso,
                const ushort_t* __restrict__ frag,
                ushort_t* __restrict__ r1buf,
                float* __restrict__ out, float* __restrict__ out_sfc,
                float* __restrict__ new_mem) {
  const ushort_t* W1f = frag;
  const ushort_t* W2f = frag + 40960;
  const ushort_t* WlF = frag + 73728;
  const ushort_t* WcF = frag + 74752;
  const ushort_t* WsF = frag + 75776;

  __shared__ __align__(16) ushort_t xh1[16 * SX];     // x 0..63 | h1 64..127
  __shared__ __align__(16) ushort_t xh2[16 * SX];     // r1 0..63 | h2 64..127
  __shared__ __align__(16) ushort_t memAll[16 * SM];  // [row][t*16+m] bf16
  __shared__ __align__(16) float    preactS[16 * SP]; // [row][g*68+unit]
  __shared__ __align__(16) ushort_t inmB[16 * SI];    // [row][t*4+c] bf16

  const int tid  = threadIdx.x;
  const int lane = tid & 63;
  const int wv   = tid >> 6;       // 0..7
  const int wq   = wv >> 1;        // unit block
  const int gp   = wv & 1;         // gate pair
  const int ln   = lane & 15;
  const int lq   = lane >> 4;
  const int u    = wq * 16 + ln;   // GEMM tile column (unit)
  const int r0   = 2 * wv;         // epilogue rows r0, r0+1 ; unit = lane
  const int b0   = blockIdx.x * ROWS;

  // B-fragments for this wave's 2 gates (LSTM1: 5 ks)
  short8 Bf[2][5];
#pragma unroll
  for (int gi = 0; gi < 2; ++gi) {
    int g = 2 * gp + gi;
#pragma unroll
    for (int ks = 0; ks < 5; ++ks)
      Bf[gi][ks] = *(const short8*)(W1f + (((wq * 4 + g) * 5 + ks) << 9) + (lane << 3));
  }
  float bg[2];
#pragma unroll
  for (int gi = 0; gi < 2; ++gi)
    bg[gi] = bih1[(2 * gp + gi) * 64 + u] + bhh1[(2 * gp + gi) * 64 + u];

  // x-generator weights: one hidden column per thread (col = lane)
  f4v wif = *(const f4v*)(Wi + lane * 4);
  float bif = bi[lane];

  // ---- stage inputs (bf16) ----
  for (int e = tid; e < 16 * 240; e += TPB) {
    int r = e / 240, c = e - r * 240;
    inmB[r * SI + c] = f2bu(inputs_main[(size_t)(b0 + r) * 240 + c]);
  }
  for (int e = tid; e < 16 * 960; e += TPB) {
    int r = e / 960, c = e - r * 960;
    memAll[r * SM + c] = f2bu(rnn1_mem[(size_t)(b0 + r) * 960 + c]);
  }
  __syncthreads();

  // ---- prologue: x(59), h1/c1 init ----
  float c1[2];
  {
    float w10 = Ws1[lane * 3 + 0], w11 = Ws1[lane * 3 + 1], w12 = Ws1[lane * 3 + 2], bb1 = bs1[lane];
    float w20 = Ws2[lane * 3 + 0], w21 = Ws2[lane * 3 + 1], w22 = Ws2[lane * 3 + 2], bb2 = bs2[lane];
#pragma unroll
    for (int i = 0; i < 2; ++i) {
      int row = r0 + i;
      const float* ax = inputs_aux + (size_t)(b0 + row) * 3;
      float a0 = ax[0], a1 = ax[1], a2 = ax[2];
      xh1[row * SX + 64 + lane] = f2bu(tanh_(w10 * a0 + w11 * a1 + w12 * a2 + bb1));
      c1[i] = tanh_(w20 * a0 + w21 * a1 + w22 * a2 + bb2);
      short4v xi = *(const short4v*)(inmB + row * SI + 59 * 4);
      float a = bif;
#pragma unroll
      for (int c = 0; c < 4; ++c) a += wif[c] * b2fu((ushort_t)xi[c]);
      xh1[row * SX + lane] = f2bu(tanh_(a));
    }
  }
  __syncthreads();

  // r1 store pointers (t descending)
  ushort_t* r1w = r1buf + ((size_t)(b0 + r0) * 60 + 59) * 64 + lane;

  // ---- LSTM1: t = 59..0 ----
  for (int t = NLAY - 1; t >= 0; --t) {
    const ushort_t* xrow = xh1 + ln * SX;
    short8 af0 = *(const short8*)(xrow + lq * 8);
    short8 af1 = *(const short8*)(xrow + 32 + lq * 8);
    short8 af2 = *(const short8*)(xrow + 64 + lq * 8);
    short8 af3 = *(const short8*)(xrow + 96 + lq * 8);
    short8 af4 = {};
    if (lq < 2) af4 = *(const short8*)(memAll + ln * SM + t * 16 + lq * 8);

    f32x4 acc[2];
#pragma unroll
    for (int gi = 0; gi < 2; ++gi) acc[gi] = (f32x4){bg[gi], bg[gi], bg[gi], bg[gi]};
#pragma unroll
    for (int gi = 0; gi < 2; ++gi) {
      acc[gi] = mfma16(af0, Bf[gi][0], acc[gi]);
      acc[gi] = mfma16(af1, Bf[gi][1], acc[gi]);
      acc[gi] = mfma16(af2, Bf[gi][2], acc[gi]);
      acc[gi] = mfma16(af3, Bf[gi][3], acc[gi]);
      acc[gi] = mfma16(af4, Bf[gi][4], acc[gi]);
    }

    // x(t-1) generation (independent of MFMA)
    float xg[2];
    if (t > 0) {
#pragma unroll
      for (int i = 0; i < 2; ++i) {
        short4v xi = *(const short4v*)(inmB + (r0 + i) * SI + (t - 1) * 4);
        float a = bif;
#pragma unroll
        for (int c = 0; c < 4; ++c) a += wif[c] * b2fu((ushort_t)xi[c]);
        xg[i] = tanh_(a);
      }
    }

    // scatter preacts to LDS
#pragma unroll
    for (int gi = 0; gi < 2; ++gi)
#pragma unroll
      for (int reg = 0; reg < 4; ++reg)
        preactS[(lq * 4 + reg) * SP + (2 * gp + gi) * 68 + u] = acc[gi][reg];
    __syncthreads();

    // epilogue: 2 cells/thread
    float pa[2][4];
#pragma unroll
    for (int i = 0; i < 2; ++i)
#pragma unroll
      for (int g = 0; g < 4; ++g)
        pa[i][g] = preactS[(r0 + i) * SP + g * 68 + lane];
#pragma unroll
    for (int i = 0; i < 2; ++i) {
      float ig = sigm_(pa[i][0]);
      float fg = sigm_(pa[i][1]);
      float gg = tanh_(pa[i][2]);
      float og = sigm_(pa[i][3]);
      float c  = fg * c1[i] + ig * gg;
      c1[i] = c;
      ushort_t hu = f2bu(og * tanh_(c));
      r1w[(size_t)i * 3840] = hu;                       // 3840 = 60*64
      if (t > 0) xh1[(r0 + i) * SX + 64 + lane] = hu;
      else       xh2[(r0 + i) * SX + lane]      = hu;   // seed r1(0)
    }
    if (t > 0) {
      xh1[r0 * SX + lane]       = f2bu(xg[0]);
      xh1[(r0 + 1) * SX + lane] = f2bu(xg[1]);
    }
    r1w -= 64;
    __syncthreads();
  }

  // ---- LSTM2 setup ----
#pragma unroll
  for (int gi = 0; gi < 2; ++gi) {
    int g = 2 * gp + gi;
#pragma unroll
    for (int ks = 0; ks < 4; ++ks)
      Bf[gi][ks] = *(const short8*)(W2f + (((wq * 4 + g) * 4 + ks) << 9) + (lane << 3));
  }
#pragma unroll
  for (int gi = 0; gi < 2; ++gi)
    bg[gi] = bih2[(2 * gp + gi) * 64 + u] + bhh2[(2 * gp + gi) * 64 + u];

  float c2[2];
  {
    float wt1u = Wt1[lane], wt2u = Wt2[lane], bt1u = bt1[lane], bt2u = bt2[lane];
#pragma unroll
    for (int i = 0; i < 2; ++i) {
      int row = r0 + i;
      float toa = inputs_aux[(size_t)(b0 + row) * 3 + 1];
      xh2[row * SX + 64 + lane] = f2bu(toa * wt1u + bt1u);
      c2[i] = toa * wt2u + bt2u;
    }
  }
  short8 PW0 = {}, PW1 = {};
  float pbias = 0.0f;
  if (wv == 0) {
    PW0 = *(const short8*)(WlF + (lane << 3));
    PW1 = *(const short8*)(WlF + 512 + (lane << 3));
    pbias = bl[ln];
  } else if (wv == 1) {
    PW0 = *(const short8*)(WcF + (lane << 3));
    PW1 = *(const short8*)(WcF + 512 + (lane << 3));
    if (ln < 4) {
      float a = bo[ln];
#pragma unroll
      for (int m = 0; m < 16; ++m) a += Wo[ln * 16 + m] * bl[m];
      pbias = a;
    }
  } else if (wv == 2) {
    PW0 = *(const short8*)(WsF + (lane << 3));
    PW1 = *(const short8*)(WsF + 512 + (lane << 3));
    pbias = (ln < 3) ? bso[ln] : 0.0f;
  }
  const ushort_t* r1rp = r1buf + ((size_t)(b0 + r0) * 60 + 1) * 64 + lane;
  float* nmp = new_mem + (size_t)(b0 + lq * 4) * 960 + ln;          // 960 = 60*16
  float* obp = out + (size_t)(b0 + lq * 4) * 240 + ln;              // 240 = 60*4
  __syncthreads();

  // ---- LSTM2: t = 0..59 ----
  for (int t = 0; t < NLAY; ++t) {
    ushort_t r1a = 0, r1b = 0;
    if (t < 59) { r1a = r1rp[0]; r1b = r1rp[3840]; }

    const ushort_t* xrow = xh2 + ln * SX;
    short8 af0 = *(const short8*)(xrow + lq * 8);
    short8 af1 = *(const short8*)(xrow + 32 + lq * 8);
    short8 af2 = *(const short8*)(xrow + 64 + lq * 8);
    short8 af3 = *(const short8*)(xrow + 96 + lq * 8);

    f32x4 acc[2];
#pragma unroll
    for (int gi = 0; gi < 2; ++gi) acc[gi] = (f32x4){bg[gi], bg[gi], bg[gi], bg[gi]};
#pragma unroll
    for (int gi = 0; gi < 2; ++gi) {
      acc[gi] = mfma16(af0, Bf[gi][0], acc[gi]);
      acc[gi] = mfma16(af1, Bf[gi][1], acc[gi]);
      acc[gi] = mfma16(af2, Bf[gi][2], acc[gi]);
      acc[gi] = mfma16(af3, Bf[gi][3], acc[gi]);
    }

    if (t > 0 && wv < 2) {  // projections for h2(t-1), still resident pre-barrier
      short8 aL0 = *(const short8*)(xrow + 64 + lq * 8);
      short8 aL1 = *(const short8*)(xrow + 96 + lq * 8);
      f32x4 ap = (f32x4){pbias, pbias, pbias, pbias};
      ap = mfma16(aL0, PW0, ap);
      ap = mfma16(aL1, PW1, ap);
      if (wv == 0) {
#pragma unroll
        for (int reg = 0; reg < 4; ++reg) nmp[reg * 960] = ap[reg];
        nmp += 16;
      } else {
        if (ln < 4) {
#pragma unroll
          for (int reg = 0; reg < 4; ++reg) obp[reg * 240] = ap[reg];
        }
        obp += 4;
      }
    }

#pragma unroll
    for (int gi = 0; gi < 2; ++gi)
#pragma unroll
      for (int reg = 0; reg < 4; ++reg)
        preactS[(lq * 4 + reg) * SP + (2 * gp + gi) * 68 + u] = acc[gi][reg];
    __syncthreads();

    float pa[2][4];
#pragma unroll
    for (int i = 0; i < 2; ++i)
#pragma unroll
      for (int g = 0; g < 4; ++g)
        pa[i][g] = preactS[(r0 + i) * SP + g * 68 + lane];
#pragma unroll
    for (int i = 0; i < 2; ++i) {
      float ig = sigm_(pa[i][0]);
      float fg = sigm_(pa[i][1]);
      float gg = tanh_(pa[i][2]);
      float og = sigm_(pa[i][3]);
      float c  = fg * c2[i] + ig * gg;
      c2[i] = c;
      xh2[(r0 + i) * SX + 64 + lane] = f2bu(og * tanh_(c));
    }
    if (t < 59) {
      xh2[r0 * SX + lane]       = r1a;
      xh2[(r0 + 1) * SX + lane] = r1b;
      r1rp += 64;
    }
    __syncthreads();
  }

  // ---- tail: t=59 projections + out_sfc ----
  if (wv < 3) {
    const ushort_t* xrow = xh2 + ln * SX;
    short8 aL0 = *(const short8*)(xrow + 64 + lq * 8);
    short8 aL1 = *(const short8*)(xrow + 96 + lq * 8);
    f32x4 ap = (f32x4){pbias, pbias, pbias, pbias};
    ap = mfma16(aL0, PW0, ap);
    ap = mfma16(aL1, PW1, ap);
    if (wv == 0) {
#pragma unroll
      for (int reg = 0; reg < 4; ++reg) nmp[reg * 960] = ap[reg];
    } else if (wv == 1) {
      if (ln < 4) {
#pragma unroll
        for (int reg = 0; reg < 4; ++reg) obp[reg * 240] = ap[reg];
      }
    } else {
      if (ln < 3) {
#pragma unroll
        for (int reg = 0; reg < 4; ++reg)
          out_sfc[(size_t)(b0 + lq * 4 + reg) * 3 + ln] = ap[reg];
      }
    }
  }
}

extern "C" void kernel_launch(void* const* d_in, const int* in_sizes, int n_in,
                              void* d_out, int out_size, void* d_ws, size_t ws_size,
                              hipStream_t stream) {
  (void)in_sizes; (void)n_in; (void)out_size; (void)ws_size;
  const float* inputs_main = (const float*)d_in[0];
  const float* inputs_aux  = (const float*)d_in[1];
  const float* rnn1_mem    = (const float*)d_in[2];
  const float* Wi   = (const float*)d_in[3];
  const float* bi   = (const float*)d_in[4];
  const float* Ws1  = (const float*)d_in[5];
  const float* bs1  = (const float*)d_in[6];
  const float* Ws2  = (const float*)d_in[7];
  const float* bs2  = (const float*)d_in[8];
  const float* Wt1  = (const float*)d_in[9];
  const float* bt1  = (const float*)d_in[10];
  const float* Wt2  = (const float*)d_in[11];
  const float* bt2  = (const float*)d_in[12];
  const float* Wih1 = (const float*)d_in[13];
  const float* Whh1 = (const float*)d_in[14];
  const float* bih1 = (const float*)d_in[15];
  const float* bhh1 = (const float*)d_in[16];
  const float* Wih2 = (const float*)d_in[17];
  const float* Whh2 = (const float*)d_in[18];
  const float* bih2 = (const float*)d_in[19];
  const float* bhh2 = (const float*)d_in[20];
  const float* Wl   = (const float*)d_in[21];
  const float* bl   = (const float*)d_in[22];
  const float* Wo   = (const float*)d_in[23];
  const float* bo   = (const float*)d_in[24];
  const float* Wso  = (const float*)d_in[25];
  const float* bso  = (const float*)d_in[26];

  float* out     = (float*)d_out;
  float* out_sfc = out + (size_t)BATCH * NLAY * 4;
  float* new_mem = out_sfc + (size_t)BATCH * 3;

  ushort_t* frag  = (ushort_t*)d_ws;                          // 76800 ushorts
  ushort_t* r1buf = (ushort_t*)((char*)d_ws + 153600);        // [B][60][64] bf16

  wtranspose<<<300, 256, 0, stream>>>(Wih1, Whh1, Wih2, Whh2, Wl, Wo, Wso, frag);
  lstm_fused<<<BATCH / ROWS, TPB, 0, stream>>>(
      inputs_main, inputs_aux, rnn1_mem, Wi, bi, Ws1, bs1, Ws2, bs2,
      Wt1, bt1, Wt2, bt2, bih1, bhh1, bih2, bhh2, bl, Wo, bo, bso,
      frag, r1buf, out, out_sfc, new_mem);
}

// Round 6
// 256.653 us; speedup vs baseline: 1.1082x; 1.1082x over previous
//
#include <hip/hip_runtime.h>
#include <hip/hip_bf16.h>

#define BATCH 8192
#define NLAY  60
#define ROWS  16
#define TPB   256
#define SX    136     // xh row stride (ushort)
#define SM    968     // memAll row stride (ushort)
#define SI    244     // inm row stride (float)
#define LOG2E 1.44269504089f
#define T2L   2.88539008178f

typedef unsigned short ushort_t;
typedef __attribute__((ext_vector_type(8))) short short8;
typedef __attribute__((ext_vector_type(4))) float f32x4;
typedef __attribute__((ext_vector_type(4))) float f4v;

__device__ __forceinline__ float rcp_(float x) { return __builtin_amdgcn_rcpf(x); }
__device__ __forceinline__ float ex2_(float x) { return __builtin_amdgcn_exp2f(x); }
__device__ __forceinline__ ushort_t f2bu(float f) {
  unsigned u = __float_as_uint(f);
  return (ushort_t)((u + 0x7FFFu + ((u >> 16) & 1u)) >> 16);
}
__device__ __forceinline__ unsigned pkbf(float a, float b) {
  union { __hip_bfloat162 h; unsigned u; } c;
  c.h = __float22bfloat162_rn(make_float2(a, b));
  return c.u;
}
__device__ __forceinline__ f32x4 mfma16(short8 a, short8 b, f32x4 c) {
  return __builtin_amdgcn_mfma_f32_16x16x32_bf16(a, b, c, 0, 0, 0);
}

// ---- Pre-pass: pack weights into MFMA B-fragment order (bf16 bits) ----
// LSTM1 K-order: [x 0..63 | h 64..127 | mem 128..143 | pad 144..159]
// Gate weights PRE-SCALED: i,f,o by log2e ; g by 2*log2e (exp2-domain epilogue).
// W1f [w][g][ks5][512] @0 ; W2f [w][g][ks4][512] @40960 ; WlF @73728 ;
// WcF (Wo@Wl) @74752 ; WsF (Wso) @75776. Total 76800 ushorts.
__global__ void wtranspose(const float* __restrict__ Wih1, const float* __restrict__ Whh1,
                           const float* __restrict__ Wih2, const float* __restrict__ Whh2,
                           const float* __restrict__ Wl,   const float* __restrict__ Wo,
                           const float* __restrict__ Wso,  ushort_t* __restrict__ frag) {
  int e = blockIdx.x * 256 + threadIdx.x;
  float v;
  if (e < 40960) {
    int j = e & 7, lx = (e >> 3) & 63, rest = e >> 9;
    int ks = rest % 5, gw = rest / 5;
    int g = gw & 3, wv = gw >> 2;
    int row = g * 64 + wv * 16 + (lx & 15);
    int k = ks * 32 + (lx >> 4) * 8 + j;
    v = (k < 64)  ? Wih1[row * 80 + k]
      : (k < 128) ? Whh1[row * 64 + (k - 64)]
      : (k < 144) ? Wih1[row * 80 + 64 + (k - 128)]
      : 0.0f;
    v *= (g == 2) ? T2L : LOG2E;
  } else if (e < 73728) {
    int e2 = e - 40960;
    int j = e2 & 7, lx = (e2 >> 3) & 63, rest = e2 >> 9;
    int ks = rest & 3, g = (rest >> 2) & 3, wv = rest >> 4;
    int row = g * 64 + wv * 16 + (lx & 15);
    int k = ks * 32 + (lx >> 4) * 8 + j;
    v = (k < 64) ? Wih2[row * 64 + k] : Whh2[row * 64 + (k - 64)];
    v *= (g == 2) ? T2L : LOG2E;
  } else if (e < 74752) {
    int e3 = e - 73728;
    int j = e3 & 7, lx = (e3 >> 3) & 63, ks = e3 >> 9;
    int n = lx & 15, k = ks * 32 + (lx >> 4) * 8 + j;
    v = Wl[n * 64 + k];
  } else if (e < 75776) {
    int e4 = e - 74752;
    int j = e4 & 7, lx = (e4 >> 3) & 63, ks = e4 >> 9;
    int n = lx & 15, k = ks * 32 + (lx >> 4) * 8 + j;
    v = 0.0f;
    if (n < 4) {
#pragma unroll
      for (int m = 0; m < 16; ++m) v += Wo[n * 16 + m] * Wl[m * 64 + k];
    }
  } else {
    int e5 = e - 75776;
    int j = e5 & 7, lx = (e5 >> 3) & 63, ks = e5 >> 9;
    int n = lx & 15, k = ks * 32 + (lx >> 4) * 8 + j;
    v = (n < 3) ? Wso[n * 64 + k] : 0.0f;
  }
  frag[e] = f2bu(v);
}

// ---- Fused LSTM: 512 blocks x 256 thr, 16 rows/block. Global ops batched
// per 4 steps so barriers drain only LDS on 3 of 4 steps. ----
__global__ __launch_bounds__(TPB, 2)
void lstm_fused(const float* __restrict__ inputs_main, const float* __restrict__ inputs_aux,
                const float* __restrict__ rnn1_mem,
                const float* __restrict__ Wi,  const float* __restrict__ bi,
                const float* __restrict__ Ws1, const float* __restrict__ bs1,
                const float* __restrict__ Ws2, const float* __restrict__ bs2,
                const float* __restrict__ Wt1, const float* __restrict__ bt1,
                const float* __restrict__ Wt2, const float* __restrict__ bt2,
                const float* __restrict__ bih1, const float* __restrict__ bhh1,
                const float* __restrict__ bih2, const float* __restrict__ bhh2,
                const float* __restrict__ bl,  const float* __restrict__ Wo,
                const float* __restrict__ bo,  const float* __restrict__ bso,
                const ushort_t* __restrict__ frag,
                ushort_t* __restrict__ r1buf,
                float* __restrict__ out, float* __restrict__ out_sfc,
                float* __restrict__ new_mem) {
  const ushort_t* W1f = frag;
  const ushort_t* W2f = frag + 40960;
  const ushort_t* WlF = frag + 73728;
  const ushort_t* WcF = frag + 74752;
  const ushort_t* WsF = frag + 75776;

  __shared__ __align__(16) ushort_t xh[2][16 * SX];   // LSTM1: x|h1 ; LSTM2: r1|h2
  __shared__ __align__(16) ushort_t memAll[16 * SM];  // [row][t*16+m] bf16
  __shared__ __align__(16) float    inm[16 * SI];     // [row][t*4+c] fp32

  const int tid = threadIdx.x;
  const int lane = tid & 63, w = tid >> 6;
  const int ln = lane & 15, lq = lane >> 4;
  const int u = w * 16 + ln;
  const int rowbase = lq * 4;
  const int b0 = blockIdx.x * ROWS;
  const int xr = tid >> 4, xm = tid & 15, xc0 = xm * 4;
  const int rr8 = tid >> 3, ch8 = tid & 7;

  ushort_t* r1blk = r1buf + (size_t)blockIdx.x * (60 * 16 * 64);

  // B1 fragments (prescaled weights)
  short8 B1f[4][5];
#pragma unroll
  for (int g = 0; g < 4; ++g)
#pragma unroll
    for (int ks = 0; ks < 5; ++ks)
      B1f[g][ks] = *(const short8*)(W1f + (((w * 4 + g) * 5 + ks) << 9) + (lane << 3));
  float bg1[4];
#pragma unroll
  for (int g = 0; g < 4; ++g)
    bg1[g] = (bih1[g * 64 + u] + bhh1[g * 64 + u]) * ((g == 2) ? T2L : LOG2E);

  // x-generator weights, prescaled by 2*log2e
  f4v wif[4];
#pragma unroll
  for (int cc = 0; cc < 4; ++cc) wif[cc] = *(const f4v*)(Wi + (xc0 + cc) * 4) * T2L;
  f4v bifv = *(const f4v*)(bi + xc0) * T2L;

  // ---- stage static inputs ----
  for (int e = tid; e < 16 * 240; e += TPB) {
    int r = e / 240, c = e - r * 240;
    inm[r * SI + c] = inputs_main[(size_t)(b0 + r) * 240 + c];
  }
  for (int e = tid; e < 16 * 960; e += TPB) {
    int r = e / 960, c = e - r * 960;
    memAll[r * SM + c] = f2bu(rnn1_mem[(size_t)(b0 + r) * 960 + c]);
  }
  __syncthreads();

  // ---- prologue: x(59) + h1/c1 init into buffer 0 ----
  float ct1[4];   // cell state in 2*log2e-scaled domain
  {
    f4v xin = *(const f4v*)&inm[xr * SI + 59 * 4];
    float xp[4];
#pragma unroll
    for (int cc = 0; cc < 4; ++cc) {
      float a = fmaf(wif[cc][3], xin[3], fmaf(wif[cc][2], xin[2],
                fmaf(wif[cc][1], xin[1], fmaf(wif[cc][0], xin[0], bifv[cc]))));
      xp[cc] = fmaf(rcp_(1.0f + ex2_(a)), -2.0f, 1.0f);
    }
    *(uint2*)&xh[0][xr * SX + xc0] = make_uint2(pkbf(xp[0], xp[1]), pkbf(xp[2], xp[3]));

    float w10 = Ws1[u * 3 + 0] * T2L, w11 = Ws1[u * 3 + 1] * T2L, w12 = Ws1[u * 3 + 2] * T2L;
    float bb1 = bs1[u] * T2L;
    float w20 = Ws2[u * 3 + 0] * T2L, w21 = Ws2[u * 3 + 1] * T2L, w22 = Ws2[u * 3 + 2] * T2L;
    float bb2 = bs2[u] * T2L;
#pragma unroll
    for (int reg = 0; reg < 4; ++reg) {
      int row = rowbase + reg;
      const float* ax = inputs_aux + (size_t)(b0 + row) * 3;
      float a0 = ax[0], a1 = ax[1], a2 = ax[2];
      float ha = w10 * a0 + w11 * a1 + w12 * a2 + bb1;
      xh[0][row * SX + 64 + u] = f2bu(fmaf(rcp_(1.0f + ex2_(ha)), -2.0f, 1.0f));
      float ca = w20 * a0 + w21 * a1 + w22 * a2 + bb2;
      ct1[reg] = fmaf(rcp_(1.0f + ex2_(ca)), -2.0f * T2L, T2L);
    }
  }
  __syncthreads();

  ushort_t* r1t = r1blk + rowbase * 64 + u;
  unsigned sxv[4], syv[4];
  int pb = 0;

  // ---- LSTM1: t = 59..0 in groups of 4; r1 flushed once per group ----
  for (int tg = 14; tg >= 0; --tg) {
#pragma unroll
    for (int s = 3; s >= 0; --s) {
      const int t = tg * 4 + s;
      const int nb = pb ^ 1;
      const ushort_t* xrow = &xh[pb][ln * SX];
      short8 af0 = *(const short8*)(xrow + lq * 8);
      short8 af1 = *(const short8*)(xrow + 32 + lq * 8);
      short8 af2 = *(const short8*)(xrow + 64 + lq * 8);
      short8 af3 = *(const short8*)(xrow + 96 + lq * 8);
      short8 af4 = {};
      if (lq < 2) af4 = *(const short8*)(memAll + ln * SM + t * 16 + lq * 8);

      f32x4 acc[4];
#pragma unroll
      for (int g = 0; g < 4; ++g) acc[g] = (f32x4){bg1[g], bg1[g], bg1[g], bg1[g]};
#pragma unroll
      for (int g = 0; g < 4; ++g) {
        acc[g] = mfma16(af0, B1f[g][0], acc[g]);
        acc[g] = mfma16(af1, B1f[g][1], acc[g]);
        acc[g] = mfma16(af2, B1f[g][2], acc[g]);
        acc[g] = mfma16(af3, B1f[g][3], acc[g]);
        acc[g] = mfma16(af4, B1f[g][4], acc[g]);
      }

      if (t > 0) {  // x(t-1) into next buffer
        f4v xin = *(const f4v*)&inm[xr * SI + (t - 1) * 4];
        float xp[4];
#pragma unroll
        for (int cc = 0; cc < 4; ++cc) {
          float a = fmaf(wif[cc][3], xin[3], fmaf(wif[cc][2], xin[2],
                    fmaf(wif[cc][1], xin[1], fmaf(wif[cc][0], xin[0], bifv[cc]))));
          xp[cc] = fmaf(rcp_(1.0f + ex2_(a)), -2.0f, 1.0f);
        }
        *(uint2*)&xh[nb][xr * SX + xc0] = make_uint2(pkbf(xp[0], xp[1]), pkbf(xp[2], xp[3]));
      }

      float h[4];
#pragma unroll
      for (int reg = 0; reg < 4; ++reg) {
        float si = rcp_(1.0f + ex2_(-acc[0][reg]));
        float sf = rcp_(1.0f + ex2_(-acc[1][reg]));
        float so = rcp_(1.0f + ex2_(-acc[3][reg]));
        float gt = fmaf(rcp_(1.0f + ex2_(acc[2][reg])), -2.0f * T2L, T2L);
        ct1[reg] = fmaf(sf, ct1[reg], si * gt);
        float tc = fmaf(rcp_(1.0f + ex2_(ct1[reg])), -2.0f, 1.0f);
        h[reg] = so * tc;
      }
      unsigned h01 = pkbf(h[0], h[1]), h23 = pkbf(h[2], h[3]);
      sxv[s] = h01; syv[s] = h23;              // stash; flush after the group
      if (t > 0) {
        xh[nb][(rowbase + 0) * SX + 64 + u] = (ushort_t)h01;
        xh[nb][(rowbase + 1) * SX + 64 + u] = (ushort_t)(h01 >> 16);
        xh[nb][(rowbase + 2) * SX + 64 + u] = (ushort_t)h23;
        xh[nb][(rowbase + 3) * SX + 64 + u] = (ushort_t)(h23 >> 16);
      } else {                                  // r1(0) seeds LSTM2 input region
        xh[nb][(rowbase + 0) * SX + u] = (ushort_t)h01;
        xh[nb][(rowbase + 1) * SX + u] = (ushort_t)(h01 >> 16);
        xh[nb][(rowbase + 2) * SX + u] = (ushort_t)h23;
        xh[nb][(rowbase + 3) * SX + u] = (ushort_t)(h23 >> 16);
      }
      __syncthreads();
      pb = nb;
    }
    // flush r1 for tt = tg*4 .. tg*4+3 (drains at a later barrier)
    ushort_t* rp = r1t + (tg << 12);
#pragma unroll
    for (int s = 0; s < 4; ++s) {
      unsigned a = sxv[s], b = syv[s];
      rp[s * 1024 + 0 * 64] = (ushort_t)a;
      rp[s * 1024 + 1 * 64] = (ushort_t)(a >> 16);
      rp[s * 1024 + 2 * 64] = (ushort_t)b;
      rp[s * 1024 + 3 * 64] = (ushort_t)(b >> 16);
    }
  }

  // ---- LSTM2 setup ----
  short8 B2f[4][4];
#pragma unroll
  for (int g = 0; g < 4; ++g)
#pragma unroll
    for (int ks = 0; ks < 4; ++ks)
      B2f[g][ks] = *(const short8*)(W2f + (((w * 4 + g) * 4 + ks) << 9) + (lane << 3));
  float bg2[4];
#pragma unroll
  for (int g = 0; g < 4; ++g)
    bg2[g] = (bih2[g * 64 + u] + bhh2[g * 64 + u]) * ((g == 2) ? T2L : LOG2E);

  float ct2[4];
  {
    float wt1u = Wt1[u], wt2u = Wt2[u], bt1u = bt1[u], bt2u = bt2[u];
#pragma unroll
    for (int reg = 0; reg < 4; ++reg) {
      int row = rowbase + reg;
      float toa = inputs_aux[(size_t)(b0 + row) * 3 + 1];
      xh[pb][row * SX + 64 + u] = f2bu(toa * wt1u + bt1u);   // no tanh (ref)
      ct2[reg] = (toa * wt2u + bt2u) * T2L;
    }
  }
  short8 PW0 = {}, PW1 = {};
  float pbias = 0.0f;
  if (w == 0) {
    PW0 = *(const short8*)(WlF + (lane << 3));
    PW1 = *(const short8*)(WlF + 512 + (lane << 3));
    pbias = bl[ln];
  } else if (w == 1) {
    PW0 = *(const short8*)(WcF + (lane << 3));
    PW1 = *(const short8*)(WcF + 512 + (lane << 3));
    if (ln < 4) {
      float a = bo[ln];
#pragma unroll
      for (int m = 0; m < 16; ++m) a += Wo[ln * 16 + m] * bl[m];
      pbias = a;
    }
  } else if (w == 2) {
    PW0 = *(const short8*)(WsF + (lane << 3));
    PW1 = *(const short8*)(WsF + 512 + (lane << 3));
    pbias = (ln < 3) ? bso[ln] : 0.0f;
  }
  const ushort_t* r1rp = r1blk + 1024 + rr8 * 64 + ch8 * 8;
  float* nmb = new_mem + (size_t)(b0 + rowbase) * 960 + ln;
  float* outb = out + (size_t)(b0 + rowbase) * 240 + ln;
  f32x4 pst[4];
  __syncthreads();

  // ---- LSTM2: t = 0..59 in groups of 4; proj stores flushed per group ----
  for (int tg = 0; tg < 15; ++tg) {
#pragma unroll
    for (int s = 0; s < 4; ++s) {
      const int t = tg * 4 + s;
      const int nb = pb ^ 1;
      short8 r1v = {};
      if (t < 59 && tid < 128) r1v = *(const short8*)(r1rp + t * 1024);

      const ushort_t* xrow = &xh[pb][ln * SX];
      short8 af0 = *(const short8*)(xrow + lq * 8);
      short8 af1 = *(const short8*)(xrow + 32 + lq * 8);
      short8 af2 = *(const short8*)(xrow + 64 + lq * 8);
      short8 af3 = *(const short8*)(xrow + 96 + lq * 8);

      f32x4 acc[4];
#pragma unroll
      for (int g = 0; g < 4; ++g) acc[g] = (f32x4){bg2[g], bg2[g], bg2[g], bg2[g]};
#pragma unroll
      for (int g = 0; g < 4; ++g) {
        acc[g] = mfma16(af0, B2f[g][0], acc[g]);
        acc[g] = mfma16(af1, B2f[g][1], acc[g]);
        acc[g] = mfma16(af2, B2f[g][2], acc[g]);
        acc[g] = mfma16(af3, B2f[g][3], acc[g]);
      }

      if (t > 0 && w < 2) {  // projection of h2(t-1) — reuses af2/af3
        f32x4 ap = (f32x4){pbias, pbias, pbias, pbias};
        ap = mfma16(af2, PW0, ap);
        ap = mfma16(af3, PW1, ap);
        pst[(t - 1) & 3] = ap;
      }

      float h[4];
#pragma unroll
      for (int reg = 0; reg < 4; ++reg) {
        float si = rcp_(1.0f + ex2_(-acc[0][reg]));
        float sf = rcp_(1.0f + ex2_(-acc[1][reg]));
        float so = rcp_(1.0f + ex2_(-acc[3][reg]));
        float gt = fmaf(rcp_(1.0f + ex2_(acc[2][reg])), -2.0f * T2L, T2L);
        ct2[reg] = fmaf(sf, ct2[reg], si * gt);
        float tc = fmaf(rcp_(1.0f + ex2_(ct2[reg])), -2.0f, 1.0f);
        h[reg] = so * tc;
      }
      unsigned h01 = pkbf(h[0], h[1]), h23 = pkbf(h[2], h[3]);
      xh[nb][(rowbase + 0) * SX + 64 + u] = (ushort_t)h01;
      xh[nb][(rowbase + 1) * SX + 64 + u] = (ushort_t)(h01 >> 16);
      xh[nb][(rowbase + 2) * SX + 64 + u] = (ushort_t)h23;
      xh[nb][(rowbase + 3) * SX + 64 + u] = (ushort_t)(h23 >> 16);
      if (t < 59 && tid < 128)
        *(short8*)&xh[nb][rr8 * SX + ch8 * 8] = r1v;
      __syncthreads();
      pb = nb;
    }
    // flush projections: slots 0,1,2 -> pt = tg*4+{0,1,2}; slot 3 -> pt = tg*4-1
    if (w < 2) {
      const int base = tg * 4;
#pragma unroll
      for (int k = 0; k < 4; ++k) {
        const int pt = (k == 3) ? base - 1 : base + k;
        if (pt < 0) continue;
        f32x4 ap = pst[k];
        if (w == 0) {
#pragma unroll
          for (int reg = 0; reg < 4; ++reg) nmb[reg * 960 + pt * 16] = ap[reg];
        } else if (ln < 4) {
#pragma unroll
          for (int reg = 0; reg < 4; ++reg) outb[reg * 240 + pt * 4] = ap[reg];
        }
      }
    }
  }

  // ---- tail: pt = 59 projections + out_sfc from final h2 (xh[pb]) ----
  if (w < 3) {
    const ushort_t* xrow = &xh[pb][ln * SX];
    short8 aL0 = *(const short8*)(xrow + 64 + lq * 8);
    short8 aL1 = *(const short8*)(xrow + 96 + lq * 8);
    f32x4 ap = (f32x4){pbias, pbias, pbias, pbias};
    ap = mfma16(aL0, PW0, ap);
    ap = mfma16(aL1, PW1, ap);
    if (w == 0) {
#pragma unroll
      for (int reg = 0; reg < 4; ++reg) nmb[reg * 960 + 59 * 16] = ap[reg];
    } else if (w == 1) {
      if (ln < 4) {
#pragma unroll
        for (int reg = 0; reg < 4; ++reg) outb[reg * 240 + 59 * 4] = ap[reg];
      }
    } else {
      if (ln < 3) {
#pragma unroll
        for (int reg = 0; reg < 4; ++reg)
          out_sfc[(size_t)(b0 + rowbase + reg) * 3 + ln] = ap[reg];
      }
    }
  }
}

extern "C" void kernel_launch(void* const* d_in, const int* in_sizes, int n_in,
                              void* d_out, int out_size, void* d_ws, size_t ws_size,
                              hipStream_t stream) {
  (void)in_sizes; (void)n_in; (void)out_size; (void)ws_size;
  const float* inputs_main = (const float*)d_in[0];
  const float* inputs_aux  = (const float*)d_in[1];
  const float* rnn1_mem    = (const float*)d_in[2];
  const float* Wi   = (const float*)d_in[3];
  const float* bi   = (const float*)d_in[4];
  const float* Ws1  = (const float*)d_in[5];
  const float* bs1  = (const float*)d_in[6];
  const float* Ws2  = (const float*)d_in[7];
  const float* bs2  = (const float*)d_in[8];
  const float* Wt1  = (const float*)d_in[9];
  const float* bt1  = (const float*)d_in[10];
  const float* Wt2  = (const float*)d_in[11];
  const float* bt2  = (const float*)d_in[12];
  const float* Wih1 = (const float*)d_in[13];
  const float* Whh1 = (const float*)d_in[14];
  const float* bih1 = (const float*)d_in[15];
  const float* bhh1 = (const float*)d_in[16];
  const float* Wih2 = (const float*)d_in[17];
  const float* Whh2 = (const float*)d_in[18];
  const float* bih2 = (const float*)d_in[19];
  const float* bhh2 = (const float*)d_in[20];
  const float* Wl   = (const float*)d_in[21];
  const float* bl   = (const float*)d_in[22];
  const float* Wo   = (const float*)d_in[23];
  const float* bo   = (const float*)d_in[24];
  const float* Wso  = (const float*)d_in[25];
  const float* bso  = (const float*)d_in[26];

  float* out     = (float*)d_out;
  float* out_sfc = out + (size_t)BATCH * NLAY * 4;
  float* new_mem = out_sfc + (size_t)BATCH * 3;

  ushort_t* frag  = (ushort_t*)d_ws;                          // 76800 ushorts
  ushort_t* r1buf = (ushort_t*)((char*)d_ws + 153600);        // [block][60][16][64] bf16

  wtranspose<<<300, 256, 0, stream>>>(Wih1, Whh1, Wih2, Whh2, Wl, Wo, Wso, frag);
  lstm_fused<<<BATCH / ROWS, TPB, 0, stream>>>(
      inputs_main, inputs_aux, rnn1_mem, Wi, bi, Ws1, bs1, Ws2, bs2,
      Wt1, bt1, Wt2, bt2, bih1, bhh1, bih2, bhh2, bl, Wo, bo, bso,
      frag, r1buf, out, out_sfc, new_mem);
}